// Round 1
// baseline (1092.302 us; speedup 1.0000x reference)
//
#include <hip/hip_runtime.h>
#include <hip/hip_bf16.h>

// ---------------- problem constants ----------------
constexpr int N_ROWS = 4096;
constexpr int VOCAB  = 50000;
constexpr int DIM    = 300;
constexpr int DP     = 320;           // DIM padded to 10 * 32 (MFMA K-steps)
constexpr long long VP = 50176;       // VOCAB padded to 8 * 6272
constexpr int VSLICE = 8;             // vocab slices (one per XCD)
constexpr int SLICE  = 6272;          // VP / VSLICE = 196 * 32
constexpr int BK     = 32;            // vocab rows per tile
constexpr int NTILE  = 196;           // SLICE / BK
constexpr int BM     = 128;           // q rows per block (8 waves * 16)
constexpr int RB     = 32;            // N_ROWS / BM

typedef __attribute__((ext_vector_type(8))) short short8;   // 8 x bf16
typedef __attribute__((ext_vector_type(4))) float floatx4;
typedef __attribute__((ext_vector_type(4))) unsigned int uintx4;

// ---------------- workspace layout (bytes) ----------------
constexpr size_t OFF_PROJ_HI = 0;                         // bf16 [4096][320]
constexpr size_t OFF_PROJ_LO = 2621440;                   // bf16 [4096][320]
constexpr size_t OFF_SDEF    = 5242880;                   // f32  [4096]
constexpr size_t OFF_VH      = 5259264;                   // bf16 [50176][320]
constexpr size_t OFF_VL      = 37371904;                  // bf16 [50176][320]
constexpr size_t OFF_VT      = 69484544;                  // bf16 [320][50176]
constexpr size_t OFF_OP      = 101597184;                 // f32  [8][4096][320]
constexpr size_t OFF_MP      = 143540224;                 // f32  [8][4096]
constexpr size_t OFF_LP      = 143671296;                 // f32  [8][4096]

static __device__ __forceinline__ unsigned short f2bf(float x) {
    __hip_bfloat16 h = __float2bfloat16(x);
    return *reinterpret_cast<unsigned short*>(&h);
}
static __device__ __forceinline__ float bf2f(unsigned short u) {
    __hip_bfloat16 h = *reinterpret_cast<__hip_bfloat16*>(&u);
    return __bfloat162float(h);
}

// ---------------- kernel 1: proj = words @ W, split hi/lo, s_def ----------------
__global__ __launch_bounds__(256) void k_proj(const float* __restrict__ words,
                                              const float* __restrict__ W,
                                              const float* __restrict__ de,
                                              unsigned short* __restrict__ proj_hi,
                                              unsigned short* __restrict__ proj_lo,
                                              float* __restrict__ sdef) {
    __shared__ float wrow[16][304];
    __shared__ float red[4][16];
    const int tid = threadIdx.x;
    const int r0  = blockIdx.x * 16;

    for (int i = tid; i < 16 * DIM; i += 256) {
        int r = i / DIM, c = i % DIM;
        wrow[r][c] = words[(size_t)(r0 + r) * DIM + c];
    }
    __syncthreads();

    float sd[16];
    #pragma unroll
    for (int r = 0; r < 16; ++r) sd[r] = 0.f;

    for (int jj = 0; jj < 2; ++jj) {
        int j = tid + jj * 256;
        if (j < DP) {
            float acc[16];
            #pragma unroll
            for (int r = 0; r < 16; ++r) acc[r] = 0.f;
            if (j < DIM) {
                #pragma unroll 4
                for (int k = 0; k < DIM; ++k) {
                    float wk = W[(size_t)k * DIM + j];
                    #pragma unroll
                    for (int r = 0; r < 16; ++r) acc[r] += wrow[r][k] * wk;
                }
                float dj = de[j];
                #pragma unroll
                for (int r = 0; r < 16; ++r) sd[r] += acc[r] * dj;
            }
            #pragma unroll
            for (int r = 0; r < 16; ++r) {
                float x = acc[r];
                unsigned short h = f2bf(x);
                proj_hi[(size_t)(r0 + r) * DP + j] = h;
                proj_lo[(size_t)(r0 + r) * DP + j] = f2bf(x - bf2f(h));
            }
        }
    }

    const int lane = tid & 63, wv = tid >> 6;
    #pragma unroll
    for (int r = 0; r < 16; ++r) {
        float v = sd[r];
        v += __shfl_xor(v, 32); v += __shfl_xor(v, 16);
        v += __shfl_xor(v, 8);  v += __shfl_xor(v, 4);
        v += __shfl_xor(v, 2);  v += __shfl_xor(v, 1);
        if (lane == 0) red[wv][r] = v;
    }
    __syncthreads();
    if (tid < 16) {
        sdef[r0 + tid] = red[0][tid] + red[1][tid] + red[2][tid] + red[3][tid];
    }
}

// ---------------- kernel 2: vocab -> hi/lo bf16 (padded) + transposed hi ----------------
__global__ __launch_bounds__(256) void k_vocab(const float* __restrict__ vocab,
                                               unsigned short* __restrict__ vh,
                                               unsigned short* __restrict__ vl,
                                               unsigned short* __restrict__ vt) {
    __shared__ float tile[64 * 65];
    const int tid = threadIdx.x;
    const int bv = blockIdx.x % 784, bn = blockIdx.x / 784;
    const int v0 = bv * 64, n0 = bn * 64;

    for (int i = tid; i < 64 * 64; i += 256) {
        int r = i >> 6, c = i & 63;
        int v = v0 + r, n = n0 + c;
        float x = (v < VOCAB && n < DIM) ? vocab[(size_t)v * DIM + n] : 0.f;
        tile[r * 65 + c] = x;
    }
    __syncthreads();
    for (int i = tid; i < 64 * 64; i += 256) {
        int r = i >> 6, c = i & 63;
        float x = tile[r * 65 + c];
        unsigned short h = f2bf(x);
        vh[(size_t)(v0 + r) * DP + (n0 + c)] = h;
        vl[(size_t)(v0 + r) * DP + (n0 + c)] = f2bf(x - bf2f(h));
        // transposed write: vt[n][v]
        float y = tile[c * 65 + r];
        vt[(size_t)(n0 + r) * VP + (v0 + c)] = f2bf(y);
    }
}

// ---------------- kernel 3: fused flash scores+softmax+PV ----------------
__global__ __launch_bounds__(512, 2) void k_attn(
    const unsigned short* __restrict__ proj_hi,
    const unsigned short* __restrict__ proj_lo,
    const unsigned short* __restrict__ gvh,
    const unsigned short* __restrict__ gvl,
    const unsigned short* __restrict__ gvt,
    float* __restrict__ opart,
    float* __restrict__ mpart,
    float* __restrict__ lpart) {
    // LDS: [0,20480) Vh tile (swizzled), [20480,40960) Vl tile (swizzled; P scratch aliases it in PV phase),
    //      [40960,61440) Vt tile [320 n][32 v]
    __shared__ __align__(16) char sm[61440];
    const int tid  = threadIdx.x;
    const int lane = tid & 63;
    const int wv   = tid >> 6;
    const int l15  = lane & 15;
    const int g    = lane >> 4;
    const int bs   = blockIdx.x & 7;   // vocab slice; consecutive blockIdx round-robin XCDs -> slice per XCD
    const int rb   = blockIdx.x >> 3;
    const int q0   = rb * BM + wv * 16;

    // Q fragments in registers (hi/lo), 10 K-steps of 32
    short8 qh[10], ql[10];
    {
        const unsigned short* ph = proj_hi + (size_t)(q0 + l15) * DP + g * 8;
        const unsigned short* pl = proj_lo + (size_t)(q0 + l15) * DP + g * 8;
        #pragma unroll
        for (int t = 0; t < 10; ++t) {
            qh[t] = *(const short8*)(ph + t * 32);
            ql[t] = *(const short8*)(pl + t * 32);
        }
    }

    floatx4 O[20];
    #pragma unroll
    for (int n = 0; n < 20; ++n) O[n] = (floatx4){0.f, 0.f, 0.f, 0.f};
    float mx[4] = {-1e30f, -1e30f, -1e30f, -1e30f};
    float ls[4] = {0.f, 0.f, 0.f, 0.f};

    const int vs0  = bs * SLICE;
    const int swz0 = (l15 & 7) << 4;

    for (int tau = 0; tau < NTILE; ++tau) {
        const int vbase = vs0 + tau * BK;
        __syncthreads();   // prior tile's PV readers done before restage
        // ---- cooperative staging ----
        {
            const unsigned short* th = gvh + (size_t)vbase * DP;
            const unsigned short* tl = gvl + (size_t)vbase * DP;
            #pragma unroll
            for (int i = 0; i < 3; ++i) {
                int c = tid + i * 512;
                if (c < 1280) {
                    int row = c / 40, u = c % 40;
                    uintx4 dh = *(const uintx4*)(th + row * DP + u * 8);
                    uintx4 dl = *(const uintx4*)(tl + row * DP + u * 8);
                    int dst = row * 640 + ((u * 16) ^ ((row & 7) << 4));
                    *(uintx4*)(sm + dst)         = dh;
                    *(uintx4*)(sm + 20480 + dst) = dl;
                }
            }
            #pragma unroll
            for (int i = 0; i < 3; ++i) {
                int c = tid + i * 512;
                if (c < 1280) {
                    int row = c >> 2, u = c & 3;   // row = n (0..319), u = 16B unit along v
                    uintx4 d = *(const uintx4*)(gvt + (size_t)row * VP + vbase + u * 8);
                    *(uintx4*)(sm + 40960 + row * 64 + u * 16) = d;
                }
            }
        }
        __syncthreads();

        const bool active = (vbase < VOCAB);   // block-uniform
        unsigned short pu0[4], pu1[4];
        if (active) {
            floatx4 s0 = {0.f,0.f,0.f,0.f}, s1 = {0.f,0.f,0.f,0.f};
            #pragma unroll
            for (int t = 0; t < 10; ++t) {
                const int koff = (t * 32 + g * 8) * 2;
                short8 bh0 = *(const short8*)(sm + l15 * 640 +         (koff ^ swz0));
                short8 bh1 = *(const short8*)(sm + (l15 + 16) * 640 +  (koff ^ swz0));
                short8 bl0 = *(const short8*)(sm + 20480 + l15 * 640 +        (koff ^ swz0));
                short8 bl1 = *(const short8*)(sm + 20480 + (l15 + 16) * 640 + (koff ^ swz0));
                s0 = __builtin_amdgcn_mfma_f32_16x16x32_bf16(qh[t], bh0, s0, 0, 0, 0);
                s1 = __builtin_amdgcn_mfma_f32_16x16x32_bf16(qh[t], bh1, s1, 0, 0, 0);
                s0 = __builtin_amdgcn_mfma_f32_16x16x32_bf16(ql[t], bh0, s0, 0, 0, 0);
                s1 = __builtin_amdgcn_mfma_f32_16x16x32_bf16(ql[t], bh1, s1, 0, 0, 0);
                s0 = __builtin_amdgcn_mfma_f32_16x16x32_bf16(qh[t], bl0, s0, 0, 0, 0);
                s1 = __builtin_amdgcn_mfma_f32_16x16x32_bf16(qh[t], bl1, s1, 0, 0, 0);
            }
            // mask padded vocab columns (column index = lane&15 for all 4 regs)
            if (vbase + l15 >= VOCAB)      { s0[0]=-1e30f; s0[1]=-1e30f; s0[2]=-1e30f; s0[3]=-1e30f; }
            if (vbase + 16 + l15 >= VOCAB) { s1[0]=-1e30f; s1[1]=-1e30f; s1[2]=-1e30f; s1[3]=-1e30f; }
            // online softmax (q row = g*4 + r; reduce over the 16-lane column group)
            #pragma unroll
            for (int r = 0; r < 4; ++r) {
                float tm = fmaxf(s0[r], s1[r]);
                tm = fmaxf(tm, __shfl_xor(tm, 1));
                tm = fmaxf(tm, __shfl_xor(tm, 2));
                tm = fmaxf(tm, __shfl_xor(tm, 4));
                tm = fmaxf(tm, __shfl_xor(tm, 8));
                float nm = fmaxf(mx[r], tm);
                float sc = __expf(mx[r] - nm);
                mx[r] = nm;
                unsigned short u0 = f2bf(__expf(s0[r] - nm));
                unsigned short u1 = f2bf(__expf(s1[r] - nm));
                pu0[r] = u0; pu1[r] = u1;
                float ps = bf2f(u0) + bf2f(u1);   // sum the *rounded* P for consistency
                ps += __shfl_xor(ps, 1);
                ps += __shfl_xor(ps, 2);
                ps += __shfl_xor(ps, 4);
                ps += __shfl_xor(ps, 8);
                ls[r] = ls[r] * sc + ps;
                #pragma unroll
                for (int n = 0; n < 20; ++n) O[n][r] *= sc;
            }
        }
        __syncthreads();   // all waves done reading Vl before P scratch overwrites it
        if (active) {
            char* pb = sm + 20480 + wv * 1024;   // per-wave P scratch [16 q][32 v] bf16
            #pragma unroll
            for (int r = 0; r < 4; ++r) {
                *(unsigned short*)(pb + (g * 4 + r) * 64 + l15 * 2)        = pu0[r];
                *(unsigned short*)(pb + (g * 4 + r) * 64 + (16 + l15) * 2) = pu1[r];
            }
            short8 pa = *(const short8*)(pb + l15 * 64 + g * 16);   // A-frag: P[q=l15][v-chunk]
            #pragma unroll
            for (int n = 0; n < 20; ++n) {
                short8 bvf = *(const short8*)(sm + 40960 + (n * 16 + l15) * 64 + g * 16); // B: V[v][n]
                O[n] = __builtin_amdgcn_mfma_f32_16x16x32_bf16(pa, bvf, O[n], 0, 0, 0);
            }
        }
    }

    // ---- store slice partials ----
    float* op = opart + ((size_t)bs * N_ROWS + q0) * DP;
    #pragma unroll
    for (int n = 0; n < 20; ++n) {
        #pragma unroll
        for (int r = 0; r < 4; ++r) {
            op[(size_t)(g * 4 + r) * DP + n * 16 + l15] = O[n][r];
        }
    }
    if (l15 == 0) {
        #pragma unroll
        for (int r = 0; r < 4; ++r) {
            mpart[(size_t)bs * N_ROWS + q0 + g * 4 + r] = mx[r];
            lpart[(size_t)bs * N_ROWS + q0 + g * 4 + r] = ls[r];
        }
    }
}

// ---------------- kernel 4: combine slice partials + default column ----------------
__global__ __launch_bounds__(256) void k_combine(const float* __restrict__ words,
                                                 const float* __restrict__ sdef,
                                                 const float* __restrict__ opart,
                                                 const float* __restrict__ mpart,
                                                 const float* __restrict__ lpart,
                                                 float* __restrict__ out) {
    const int gid = blockIdx.x * 256 + threadIdx.x;
    const int q = gid / DP;
    const int d = gid % DP;
    if (q >= N_ROWS) return;
    float sd = sdef[q];
    float M = sd;
    #pragma unroll
    for (int j = 0; j < VSLICE; ++j) M = fmaxf(M, mpart[(size_t)j * N_ROWS + q]);
    float ed = __expf(sd - M);
    float denom = ed;
    float acc = (d < DIM) ? ed * words[(size_t)q * DIM + d] : 0.f;
    #pragma unroll
    for (int j = 0; j < VSLICE; ++j) {
        float e = __expf(mpart[(size_t)j * N_ROWS + q] - M);
        denom += lpart[(size_t)j * N_ROWS + q] * e;
        acc += e * opart[((size_t)j * N_ROWS + q) * DP + d];
    }
    if (d < DIM) out[(size_t)q * DIM + d] = acc / denom;
}

// ---------------- launcher ----------------
extern "C" void kernel_launch(void* const* d_in, const int* in_sizes, int n_in,
                              void* d_out, int out_size, void* d_ws, size_t ws_size,
                              hipStream_t stream) {
    const float* words = (const float*)d_in[0];
    const float* vocab = (const float*)d_in[1];
    const float* de    = (const float*)d_in[2];
    const float* W     = (const float*)d_in[3];

    char* ws = (char*)d_ws;
    unsigned short* proj_hi = (unsigned short*)(ws + OFF_PROJ_HI);
    unsigned short* proj_lo = (unsigned short*)(ws + OFF_PROJ_LO);
    float*          sdef    = (float*)(ws + OFF_SDEF);
    unsigned short* vh      = (unsigned short*)(ws + OFF_VH);
    unsigned short* vl      = (unsigned short*)(ws + OFF_VL);
    unsigned short* vt      = (unsigned short*)(ws + OFF_VT);
    float*          opart   = (float*)(ws + OFF_OP);
    float*          mpart   = (float*)(ws + OFF_MP);
    float*          lpart   = (float*)(ws + OFF_LP);

    hipLaunchKernelGGL(k_proj,    dim3(N_ROWS / 16), dim3(256), 0, stream,
                       words, W, de, proj_hi, proj_lo, sdef);
    hipLaunchKernelGGL(k_vocab,   dim3(784 * 5), dim3(256), 0, stream,
                       vocab, vh, vl, vt);
    hipLaunchKernelGGL(k_attn,    dim3(RB * VSLICE), dim3(512), 0, stream,
                       proj_hi, proj_lo, vh, vl, vt, opart, mpart, lpart);
    hipLaunchKernelGGL(k_combine, dim3((N_ROWS * DP) / 256), dim3(256), 0, stream,
                       words, sdef, opart, mpart, lpart, (float*)d_out);
}

// Round 2
// 804.772 us; speedup vs baseline: 1.3573x; 1.3573x over previous
//
#include <hip/hip_runtime.h>
#include <hip/hip_bf16.h>
#include <hip/hip_fp16.h>

// ---------------- problem constants ----------------
constexpr int N_ROWS = 4096;
constexpr int VOCAB  = 50000;
constexpr int DIM    = 300;
constexpr int DP     = 320;           // DIM padded to 10 * 32
constexpr long long VP = 50176;       // VOCAB padded to 8 * 6272
constexpr int VSLICE = 8;
constexpr int SLICE  = 6272;          // 196 * 32
constexpr int BK     = 32;
constexpr int NTILE  = 196;
constexpr int RB     = 32;            // 4096 / 128

typedef __attribute__((ext_vector_type(8))) _Float16 half8;
typedef __attribute__((ext_vector_type(4))) float floatx4;

// ---------------- workspace layout (bytes) ----------------
constexpr size_t OFF_PROJ_HI = 0;                          // fp16 [4096][320]
constexpr size_t OFF_PROJ_LO = 2621440;                    // fp16 [4096][320]
constexpr size_t OFF_SDEF    = 5242880;                    // f32  [4096]
constexpr size_t OFF_VH      = 5259264;                    // fp16 [50176][320]
constexpr size_t OFF_VT      = 37371904;                   // fp16 [320][50176]
constexpr size_t OFF_OP      = 69484544;                   // f32  [8][4096][320]
constexpr size_t OFF_MP      = 111427584;                  // f32  [8][4096]
constexpr size_t OFF_LP      = 111558656;                  // f32  [8][4096]
constexpr int    VT_REL      = (int)(OFF_VT - OFF_VH);     // 32112640

static __device__ __forceinline__ unsigned short f2h(float x) {
    __half h = __float2half(x);
    return __half_as_ushort(h);
}
static __device__ __forceinline__ float h2f(unsigned short u) {
    return __half2float(__ushort_as_half(u));
}

// DPP butterfly reduction over 16-lane rows (xor-masks {1,2,7,15} span the group)
static __device__ __forceinline__ float red16_max(float x) {
    x = fmaxf(x, __int_as_float(__builtin_amdgcn_update_dpp(0, __float_as_int(x), 0xB1, 0xF, 0xF, true)));  // quad_perm [1,0,3,2]
    x = fmaxf(x, __int_as_float(__builtin_amdgcn_update_dpp(0, __float_as_int(x), 0x4E, 0xF, 0xF, true)));  // quad_perm [2,3,0,1]
    x = fmaxf(x, __int_as_float(__builtin_amdgcn_update_dpp(0, __float_as_int(x), 0x141, 0xF, 0xF, true))); // row_half_mirror
    x = fmaxf(x, __int_as_float(__builtin_amdgcn_update_dpp(0, __float_as_int(x), 0x140, 0xF, 0xF, true))); // row_mirror
    return x;
}
static __device__ __forceinline__ float red16_sum(float x) {
    x += __int_as_float(__builtin_amdgcn_update_dpp(0, __float_as_int(x), 0xB1, 0xF, 0xF, true));
    x += __int_as_float(__builtin_amdgcn_update_dpp(0, __float_as_int(x), 0x4E, 0xF, 0xF, true));
    x += __int_as_float(__builtin_amdgcn_update_dpp(0, __float_as_int(x), 0x141, 0xF, 0xF, true));
    x += __int_as_float(__builtin_amdgcn_update_dpp(0, __float_as_int(x), 0x140, 0xF, 0xF, true));
    return x;
}

static __device__ __forceinline__ void gload16(const void* g, void* l) {
    __builtin_amdgcn_global_load_lds(
        (const __attribute__((address_space(1))) unsigned int*)g,
        (__attribute__((address_space(3))) unsigned int*)l, 16, 0, 0);
}

// ---------------- kernel 1: proj = words @ W (fp16 hi/lo) + s_def ----------------
__global__ __launch_bounds__(256) void k_proj(const float* __restrict__ words,
                                              const float* __restrict__ W,
                                              const float* __restrict__ de,
                                              unsigned short* __restrict__ proj_hi,
                                              unsigned short* __restrict__ proj_lo,
                                              float* __restrict__ sdef) {
    __shared__ float wrow[16][304];
    __shared__ float red[4][16];
    const int tid = threadIdx.x;
    const int r0  = blockIdx.x * 16;

    for (int i = tid; i < 16 * DIM; i += 256) {
        int r = i / DIM, c = i % DIM;
        wrow[r][c] = words[(size_t)(r0 + r) * DIM + c];
    }
    __syncthreads();

    float sd[16];
    #pragma unroll
    for (int r = 0; r < 16; ++r) sd[r] = 0.f;

    for (int jj = 0; jj < 2; ++jj) {
        int j = tid + jj * 256;
        if (j < DP) {
            float acc[16];
            #pragma unroll
            for (int r = 0; r < 16; ++r) acc[r] = 0.f;
            if (j < DIM) {
                #pragma unroll 4
                for (int k = 0; k < DIM; ++k) {
                    float wk = W[(size_t)k * DIM + j];
                    #pragma unroll
                    for (int r = 0; r < 16; ++r) acc[r] += wrow[r][k] * wk;
                }
                float dj = de[j];
                #pragma unroll
                for (int r = 0; r < 16; ++r) sd[r] += acc[r] * dj;
            }
            #pragma unroll
            for (int r = 0; r < 16; ++r) {
                float x = acc[r];
                unsigned short h = f2h(x);
                proj_hi[(size_t)(r0 + r) * DP + j] = h;
                proj_lo[(size_t)(r0 + r) * DP + j] = f2h(x - h2f(h));
            }
        }
    }

    const int lane = tid & 63, wv = tid >> 6;
    #pragma unroll
    for (int r = 0; r < 16; ++r) {
        float v = sd[r];
        v += __shfl_xor(v, 32); v += __shfl_xor(v, 16);
        v += __shfl_xor(v, 8);  v += __shfl_xor(v, 4);
        v += __shfl_xor(v, 2);  v += __shfl_xor(v, 1);
        if (lane == 0) red[wv][r] = v;
    }
    __syncthreads();
    if (tid < 16) {
        sdef[r0 + tid] = red[0][tid] + red[1][tid] + red[2][tid] + red[3][tid];
    }
}

// ---------------- kernel 2: vocab -> fp16 (padded) + transposed fp16 ----------------
__global__ __launch_bounds__(256) void k_vocab(const float* __restrict__ vocab,
                                               unsigned short* __restrict__ vh,
                                               unsigned short* __restrict__ vt) {
    __shared__ float tile[64 * 65];
    const int tid = threadIdx.x;
    const int bv = blockIdx.x % 784, bn = blockIdx.x / 784;
    const int v0 = bv * 64, n0 = bn * 64;

    for (int i = tid; i < 64 * 64; i += 256) {
        int r = i >> 6, c = i & 63;
        int v = v0 + r, n = n0 + c;
        float x = (v < VOCAB && n < DIM) ? vocab[(size_t)v * DIM + n] : 0.f;
        tile[r * 65 + c] = x;
    }
    __syncthreads();
    // vh: pairs along n
    for (int i = tid; i < 64 * 32; i += 256) {
        int r = i >> 5, cp = i & 31;
        float x0 = tile[r * 65 + cp * 2];
        float x1 = tile[r * 65 + cp * 2 + 1];
        unsigned int pack = (unsigned int)f2h(x0) | ((unsigned int)f2h(x1) << 16);
        *(unsigned int*)(vh + (size_t)(v0 + r) * DP + n0 + cp * 2) = pack;
    }
    // vt: pairs along v
    for (int i = tid; i < 64 * 32; i += 256) {
        int rn = i >> 5, vp = i & 31;
        float y0 = tile[(vp * 2) * 65 + rn];
        float y1 = tile[(vp * 2 + 1) * 65 + rn];
        unsigned int pack = (unsigned int)f2h(y0) | ((unsigned int)f2h(y1) << 16);
        *(unsigned int*)(vt + (size_t)(n0 + rn) * VP + v0 + vp * 2) = pack;
    }
}

// ---------------- kernel 3: fused flash scores+softmax+PV (fp16, O^T PV) ----------------
// LDS: buf0 [0,40960): Vh [0,20480) swizzled, Vt [20480,40960) swizzled
//      buf1 [40960,81920); P [81920,90112) (128x64B, unit-swizzled); sc [90112,90624)
__global__ __launch_bounds__(512, 2) void k_attn(
    const unsigned short* __restrict__ proj_hi,
    const unsigned short* __restrict__ proj_lo,
    const unsigned short* __restrict__ gvh,
    float* __restrict__ opart,
    float* __restrict__ mpart,
    float* __restrict__ lpart) {
    __shared__ __align__(16) char sm[90624];
    const int tid  = threadIdx.x;
    const int lane = tid & 63;
    const int wv   = tid >> 6;
    const int l15  = lane & 15;
    const int g    = lane >> 4;
    const int bs   = blockIdx.x & 7;
    const int rb   = blockIdx.x >> 3;
    const int qblk = rb * 128;
    const int qw   = qblk + wv * 16;
    const int vs0  = bs * SLICE;
    const int swz0 = (l15 & 7) << 4;

    // Q fragments (fp16 hi/lo), 10 K-steps of 32
    half8 qh[10], ql[10];
    {
        const unsigned short* ph = proj_hi + (size_t)(qw + l15) * DP + g * 8;
        const unsigned short* pl = proj_lo + (size_t)(qw + l15) * DP + g * 8;
        #pragma unroll
        for (int t = 0; t < 10; ++t) {
            qh[t] = *(const half8*)(ph + t * 32);
            ql[t] = *(const half8*)(pl + t * 32);
        }
    }

    // staging source offsets (pre-swizzled, relative to gvh bytes)
    const char* gbase = (const char*)gvh;
    int soff[5], sstr[5];
    #pragma unroll
    for (int i = 0; i < 5; ++i) {
        const int j = i * 8 + wv;
        if (j < 20) {             // Vh unit j: 64 lanes x 16B, dst linear
            const int u = j * 64 + lane;
            const int row = u / 40, s = u - row * 40;
            soff[i] = vs0 * 640 + row * 640 + ((s ^ (row & 7)) << 4);
            sstr[i] = BK * DP * 2;   // 20480
        } else {                  // Vt unit j-20
            const int jj = j - 20;
            const int u = jj * 64 + lane;
            const int row = u >> 2, c = u & 3;
            soff[i] = VT_REL + vs0 * 2 + row * (int)(VP * 2) + ((c ^ (row & 3)) << 4);
            sstr[i] = BK * 2;        // 64
        }
    }

    floatx4 O0[8], O1[8], O2[8];
    #pragma unroll
    for (int q = 0; q < 8; ++q) {
        O0[q] = (floatx4){0.f, 0.f, 0.f, 0.f};
        O1[q] = (floatx4){0.f, 0.f, 0.f, 0.f};
        O2[q] = (floatx4){0.f, 0.f, 0.f, 0.f};
    }
    float mx[4] = {-1e30f, -1e30f, -1e30f, -1e30f};
    float ls[4] = {0.f, 0.f, 0.f, 0.f};

    char* Pb  = sm + 81920;
    float* scb = (float*)(sm + 90112);

    // prologue: stage tile 0 into buf0
    #pragma unroll
    for (int i = 0; i < 5; ++i) {
        gload16(gbase + (size_t)(unsigned)soff[i], sm + ((i * 8 + wv) << 10));
        soff[i] += sstr[i];
    }
    __syncthreads();

    for (int tau = 0; tau < NTILE; ++tau) {
        char* buf = sm + (tau & 1) * 40960;
        // stage next tile (async; completes under the mid-tile barrier's vmcnt)
        if (tau + 1 < NTILE) {
            char* nxt = sm + ((tau + 1) & 1) * 40960;
            #pragma unroll
            for (int i = 0; i < 5; ++i) {
                gload16(gbase + (size_t)(unsigned)soff[i], nxt + ((i * 8 + wv) << 10));
                soff[i] += sstr[i];
            }
        }
        // ---- QK^T: S[q=16][v=32], 2-term fp16 ----
        floatx4 s0 = {0.f,0.f,0.f,0.f}, s1 = {0.f,0.f,0.f,0.f};
        __builtin_amdgcn_s_setprio(1);
        #pragma unroll
        for (int t = 0; t < 10; ++t) {
            const int koff = (t * 4 + g) << 4;
            half8 bh0 = *(const half8*)(buf + l15 * 640 + (koff ^ swz0));
            half8 bh1 = *(const half8*)(buf + (l15 + 16) * 640 + (koff ^ swz0));
            s0 = __builtin_amdgcn_mfma_f32_16x16x32_f16(qh[t], bh0, s0, 0, 0, 0);
            s0 = __builtin_amdgcn_mfma_f32_16x16x32_f16(ql[t], bh0, s0, 0, 0, 0);
            s1 = __builtin_amdgcn_mfma_f32_16x16x32_f16(qh[t], bh1, s1, 0, 0, 0);
            s1 = __builtin_amdgcn_mfma_f32_16x16x32_f16(ql[t], bh1, s1, 0, 0, 0);
        }
        __builtin_amdgcn_s_setprio(0);
        const int vbase = vs0 + tau * BK;
        if (vbase + l15 >= VOCAB)      { s0[0]=-1e30f; s0[1]=-1e30f; s0[2]=-1e30f; s0[3]=-1e30f; }
        if (vbase + 16 + l15 >= VOCAB) { s1[0]=-1e30f; s1[1]=-1e30f; s1[2]=-1e30f; s1[3]=-1e30f; }
        // ---- online softmax (DPP reduce over 16-lane groups), defer-max THR=8 ----
        unsigned short pu0[4], pu1[4]; float scv[4];
        #pragma unroll
        for (int r = 0; r < 4; ++r) {
            float tm = red16_max(fmaxf(s0[r], s1[r]));
            bool grow = tm > mx[r] + 8.0f;
            float nm = grow ? tm : mx[r];
            float sc = grow ? __expf(mx[r] - nm) : 1.0f;
            mx[r] = nm;
            float p0 = __expf(s0[r] - nm);
            float p1 = __expf(s1[r] - nm);
            pu0[r] = f2h(p0); pu1[r] = f2h(p1);
            float ps = red16_sum(h2f(pu0[r]) + h2f(pu1[r]));
            ls[r] = ls[r] * sc + ps;
            scv[r] = sc;
        }
        // ---- publish P (fp16, unit-swizzled rows) + sc ----
        #pragma unroll
        for (int r = 0; r < 4; ++r) {
            const int q = wv * 16 + g * 4 + r;
            const int u0 = l15 >> 3;
            *(unsigned short*)(Pb + q * 64 + ((u0 ^ (q & 3)) << 4) + ((l15 & 7) * 2)) = pu0[r];
            *(unsigned short*)(Pb + q * 64 + (((u0 + 2) ^ (q & 3)) << 4) + ((l15 & 7) * 2)) = pu1[r];
            if (l15 == 0) scb[q] = scv[r];
        }
        __syncthreads();   // P/sc visible; staged loads for t+1 also drained here
        // ---- PV in O^T form: O^T[n][q] += V^T-frag x P-frag ----
        half8 pf[8];
        #pragma unroll
        for (int qb = 0; qb < 8; ++qb) {
            const int q = qb * 16 + l15;
            pf[qb] = *(const half8*)(Pb + q * 64 + ((g ^ (q & 3)) << 4));
        }
        #pragma unroll
        for (int qb = 0; qb < 8; ++qb) {
            float sc = scb[qb * 16 + l15];
            if (__any(sc != 1.0f)) {
                O0[qb] *= sc; O1[qb] *= sc; O2[qb] *= sc;
            }
        }
        __builtin_amdgcn_s_setprio(1);
        {
            const char* vtb = buf + 20480;
            int n0 = wv * 16;
            half8 af = *(const half8*)(vtb + (n0 + l15) * 64 + ((g ^ (l15 & 3)) << 4));
            #pragma unroll
            for (int qb = 0; qb < 8; ++qb)
                O0[qb] = __builtin_amdgcn_mfma_f32_16x16x32_f16(af, pf[qb], O0[qb], 0, 0, 0);
            n0 = (wv + 8) * 16;
            af = *(const half8*)(vtb + (n0 + l15) * 64 + ((g ^ (l15 & 3)) << 4));
            #pragma unroll
            for (int qb = 0; qb < 8; ++qb)
                O1[qb] = __builtin_amdgcn_mfma_f32_16x16x32_f16(af, pf[qb], O1[qb], 0, 0, 0);
            if (wv < 4) {
                n0 = (wv + 16) * 16;
                af = *(const half8*)(vtb + (n0 + l15) * 64 + ((g ^ (l15 & 3)) << 4));
                #pragma unroll
                for (int qb = 0; qb < 8; ++qb)
                    O2[qb] = __builtin_amdgcn_mfma_f32_16x16x32_f16(af, pf[qb], O2[qb], 0, 0, 0);
            }
        }
        __builtin_amdgcn_s_setprio(0);
        __syncthreads();   // everyone done with buf + P before restage/rewrite
    }

    // ---- store partials ----
    #pragma unroll
    for (int qb = 0; qb < 8; ++qb) {
        float* op = opart + ((size_t)bs * N_ROWS + qblk + qb * 16 + l15) * DP + g * 4;
        *(floatx4*)(op + wv * 16) = O0[qb];
        *(floatx4*)(op + (wv + 8) * 16) = O1[qb];
        if (wv < 4) *(floatx4*)(op + (wv + 16) * 16) = O2[qb];
    }
    if (l15 == 0) {
        #pragma unroll
        for (int r = 0; r < 4; ++r) {
            mpart[(size_t)bs * N_ROWS + qw + g * 4 + r] = mx[r];
            lpart[(size_t)bs * N_ROWS + qw + g * 4 + r] = ls[r];
        }
    }
}

// ---------------- kernel 4: combine slice partials + default column ----------------
__global__ __launch_bounds__(256) void k_combine(const float* __restrict__ words,
                                                 const float* __restrict__ sdef,
                                                 const float* __restrict__ opart,
                                                 const float* __restrict__ mpart,
                                                 const float* __restrict__ lpart,
                                                 float* __restrict__ out) {
    const int gid = blockIdx.x * 256 + threadIdx.x;
    const int q = gid / DP;
    const int d = gid % DP;
    if (q >= N_ROWS) return;
    float sd = sdef[q];
    float M = sd;
    #pragma unroll
    for (int j = 0; j < VSLICE; ++j) M = fmaxf(M, mpart[(size_t)j * N_ROWS + q]);
    float ed = __expf(sd - M);
    float denom = ed;
    float acc = (d < DIM) ? ed * words[(size_t)q * DIM + d] : 0.f;
    #pragma unroll
    for (int j = 0; j < VSLICE; ++j) {
        float e = __expf(mpart[(size_t)j * N_ROWS + q] - M);
        denom += lpart[(size_t)j * N_ROWS + q] * e;
        acc += e * opart[((size_t)j * N_ROWS + q) * DP + d];
    }
    if (d < DIM) out[(size_t)q * DIM + d] = acc / denom;
}

// ---------------- launcher ----------------
extern "C" void kernel_launch(void* const* d_in, const int* in_sizes, int n_in,
                              void* d_out, int out_size, void* d_ws, size_t ws_size,
                              hipStream_t stream) {
    const float* words = (const float*)d_in[0];
    const float* vocab = (const float*)d_in[1];
    const float* de    = (const float*)d_in[2];
    const float* W     = (const float*)d_in[3];

    char* ws = (char*)d_ws;
    unsigned short* proj_hi = (unsigned short*)(ws + OFF_PROJ_HI);
    unsigned short* proj_lo = (unsigned short*)(ws + OFF_PROJ_LO);
    float*          sdef    = (float*)(ws + OFF_SDEF);
    unsigned short* vh      = (unsigned short*)(ws + OFF_VH);
    unsigned short* vt      = (unsigned short*)(ws + OFF_VT);
    float*          opart   = (float*)(ws + OFF_OP);
    float*          mpart   = (float*)(ws + OFF_MP);
    float*          lpart   = (float*)(ws + OFF_LP);

    hipLaunchKernelGGL(k_proj,    dim3(N_ROWS / 16), dim3(256), 0, stream,
                       words, W, de, proj_hi, proj_lo, sdef);
    hipLaunchKernelGGL(k_vocab,   dim3(784 * 5), dim3(256), 0, stream,
                       vocab, vh, vt);
    hipLaunchKernelGGL(k_attn,    dim3(RB * VSLICE), dim3(512), 0, stream,
                       proj_hi, proj_lo, vh, opart, mpart, lpart);
    hipLaunchKernelGGL(k_combine, dim3((N_ROWS * DP) / 256), dim3(256), 0, stream,
                       words, sdef, opart, mpart, lpart, (float*)d_out);
}

// Round 4
// 657.206 us; speedup vs baseline: 1.6620x; 1.2245x over previous
//
#include <hip/hip_runtime.h>
#include <hip/hip_fp16.h>

// ---------------- problem constants ----------------
constexpr int N_ROWS = 4096;
constexpr int VOCAB  = 50000;
constexpr int DIM    = 300;
constexpr int DP     = 320;           // DIM padded to 10 * 32
constexpr long long VP = 50176;       // VOCAB padded to 8 * 6272
constexpr int VSLICE = 8;
constexpr int SLICE  = 6272;          // 196 * 32
constexpr int BK     = 32;
constexpr int NTILE  = 196;
constexpr int RB     = 64;            // 4096 / 64 q-rows per block

typedef __attribute__((ext_vector_type(8))) _Float16 half8;
typedef __attribute__((ext_vector_type(4))) float floatx4;
typedef __attribute__((ext_vector_type(4))) unsigned int uintx4;

// ---------------- workspace layout (bytes) ----------------
constexpr size_t OFF_PROJ_HI = 0;                          // fp16 [4096][320]
constexpr size_t OFF_PROJ_LO = 2621440;                    // fp16 [4096][320]
constexpr size_t OFF_SDEF    = 5242880;                    // f32  [4096]
constexpr size_t OFF_VH      = 5259264;                    // fp16 [50176][320]
constexpr size_t OFF_VT      = 37371904;                   // fp16 [320][50176]
constexpr size_t OFF_OP      = 69484544;                   // f32  [8][4096][320]
constexpr size_t OFF_MP      = 111427584;                  // f32  [8][4096]
constexpr size_t OFF_LP      = 111558656;                  // f32  [8][4096]

static __device__ __forceinline__ unsigned short f2h(float x) {
    __half h = __float2half(x);
    return __half_as_ushort(h);
}
static __device__ __forceinline__ float h2f(unsigned short u) {
    return __half2float(__ushort_as_half(u));
}

// DPP butterfly reduction over 16-lane rows (verified R2)
static __device__ __forceinline__ float red16_max(float x) {
    x = fmaxf(x, __int_as_float(__builtin_amdgcn_update_dpp(0, __float_as_int(x), 0xB1, 0xF, 0xF, true)));
    x = fmaxf(x, __int_as_float(__builtin_amdgcn_update_dpp(0, __float_as_int(x), 0x4E, 0xF, 0xF, true)));
    x = fmaxf(x, __int_as_float(__builtin_amdgcn_update_dpp(0, __float_as_int(x), 0x141, 0xF, 0xF, true)));
    x = fmaxf(x, __int_as_float(__builtin_amdgcn_update_dpp(0, __float_as_int(x), 0x140, 0xF, 0xF, true)));
    return x;
}
static __device__ __forceinline__ float red16_sum(float x) {
    x += __int_as_float(__builtin_amdgcn_update_dpp(0, __float_as_int(x), 0xB1, 0xF, 0xF, true));
    x += __int_as_float(__builtin_amdgcn_update_dpp(0, __float_as_int(x), 0x4E, 0xF, 0xF, true));
    x += __int_as_float(__builtin_amdgcn_update_dpp(0, __float_as_int(x), 0x141, 0xF, 0xF, true));
    x += __int_as_float(__builtin_amdgcn_update_dpp(0, __float_as_int(x), 0x140, 0xF, 0xF, true));
    return x;
}

static __device__ __forceinline__ void gload16(const void* g, void* l) {
    __builtin_amdgcn_global_load_lds(
        (const __attribute__((address_space(1))) unsigned int*)g,
        (__attribute__((address_space(3))) unsigned int*)l, 16, 0, 0);
}

// ---------------- kernel 1: proj = words @ W (fp16 hi/lo) + s_def (verified R2) ----------------
__global__ __launch_bounds__(256) void k_proj(const float* __restrict__ words,
                                              const float* __restrict__ W,
                                              const float* __restrict__ de,
                                              unsigned short* __restrict__ proj_hi,
                                              unsigned short* __restrict__ proj_lo,
                                              float* __restrict__ sdef) {
    __shared__ float wrow[16][304];
    __shared__ float red[4][16];
    const int tid = threadIdx.x;
    const int r0  = blockIdx.x * 16;

    for (int i = tid; i < 16 * DIM; i += 256) {
        int r = i / DIM, c = i % DIM;
        wrow[r][c] = words[(size_t)(r0 + r) * DIM + c];
    }
    __syncthreads();

    float sd[16];
    #pragma unroll
    for (int r = 0; r < 16; ++r) sd[r] = 0.f;

    for (int jj = 0; jj < 2; ++jj) {
        int j = tid + jj * 256;
        if (j < DP) {
            float acc[16];
            #pragma unroll
            for (int r = 0; r < 16; ++r) acc[r] = 0.f;
            if (j < DIM) {
                #pragma unroll 4
                for (int k = 0; k < DIM; ++k) {
                    float wk = W[(size_t)k * DIM + j];
                    #pragma unroll
                    for (int r = 0; r < 16; ++r) acc[r] += wrow[r][k] * wk;
                }
                float dj = de[j];
                #pragma unroll
                for (int r = 0; r < 16; ++r) sd[r] += acc[r] * dj;
            }
            #pragma unroll
            for (int r = 0; r < 16; ++r) {
                float x = acc[r];
                unsigned short h = f2h(x);
                proj_hi[(size_t)(r0 + r) * DP + j] = h;
                proj_lo[(size_t)(r0 + r) * DP + j] = f2h(x - h2f(h));
            }
        }
    }

    const int lane = tid & 63, wv = tid >> 6;
    #pragma unroll
    for (int r = 0; r < 16; ++r) {
        float v = sd[r];
        v += __shfl_xor(v, 32); v += __shfl_xor(v, 16);
        v += __shfl_xor(v, 8);  v += __shfl_xor(v, 4);
        v += __shfl_xor(v, 2);  v += __shfl_xor(v, 1);
        if (lane == 0) red[wv][r] = v;
    }
    __syncthreads();
    if (tid < 16) {
        sdef[r0 + tid] = red[0][tid] + red[1][tid] + red[2][tid] + red[3][tid];
    }
}

// ---------------- kernel 2: vocab -> fp16 (padded) + transposed fp16 (verified R2) ----------------
__global__ __launch_bounds__(256) void k_vocab(const float* __restrict__ vocab,
                                               unsigned short* __restrict__ vh,
                                               unsigned short* __restrict__ vt) {
    __shared__ float tile[64 * 65];
    const int tid = threadIdx.x;
    const int bv = blockIdx.x % 784, bn = blockIdx.x / 784;
    const int v0 = bv * 64, n0 = bn * 64;

    for (int i = tid; i < 64 * 64; i += 256) {
        int r = i >> 6, c = i & 63;
        int v = v0 + r, n = n0 + c;
        float x = (v < VOCAB && n < DIM) ? vocab[(size_t)v * DIM + n] : 0.f;
        tile[r * 65 + c] = x;
    }
    __syncthreads();
    for (int i = tid; i < 64 * 32; i += 256) {
        int r = i >> 5, cp = i & 31;
        float x0 = tile[r * 65 + cp * 2];
        float x1 = tile[r * 65 + cp * 2 + 1];
        unsigned int pack = (unsigned int)f2h(x0) | ((unsigned int)f2h(x1) << 16);
        *(unsigned int*)(vh + (size_t)(v0 + r) * DP + n0 + cp * 2) = pack;
    }
    for (int i = tid; i < 64 * 32; i += 256) {
        int rn = i >> 5, vp = i & 31;
        float y0 = tile[(vp * 2) * 65 + rn];
        float y1 = tile[(vp * 2 + 1) * 65 + rn];
        unsigned int pack = (unsigned int)f2h(y0) | ((unsigned int)f2h(y1) << 16);
        *(unsigned int*)(vt + (size_t)(n0 + rn) * VP + v0 + vp * 2) = pack;
    }
}

// ---------------- kernel 3: fused flash scores+softmax+PV ----------------
// 4 waves * 16 q = 64 q-rows per block; grid 64 rb x 8 slices; 2 blocks/CU.
// LDS: Vh buf0 [0,20480) | Vh buf1 [20480,40960) | P [40960,45056) | scb [45056,45312)
// Vt (PV A-frags) loaded straight from global to regs (read-once, no sharing).
__global__ __launch_bounds__(256, 2) void k_attn(
    const unsigned short* __restrict__ proj_hi,
    const unsigned short* __restrict__ proj_lo,
    const unsigned short* __restrict__ gvh,
    const unsigned short* __restrict__ gvt,
    float* __restrict__ opart,
    float* __restrict__ mpart,
    float* __restrict__ lpart) {
    __shared__ __align__(16) char sm[45312];
    const int tid  = threadIdx.x;
    const int lane = tid & 63;
    const int wv   = tid >> 6;     // 0..3
    const int l15  = lane & 15;
    const int g    = lane >> 4;    // 0..3
    const int bs   = blockIdx.x & 7;   // slice; consecutive blocks -> different XCDs -> slice per XCD L2
    const int rb   = blockIdx.x >> 3;
    const int qblk = rb * 64;
    const int qw   = qblk + wv * 16;
    const int vs0  = bs * SLICE;
    const int swz0 = (l15 & 7) << 4;

    // Q fragments (fp16 hi/lo), 10 K-steps of 32
    half8 qh[10], ql[10];
    {
        const unsigned short* ph = proj_hi + (size_t)(qw + l15) * DP + g * 8;
        const unsigned short* pl = proj_lo + (size_t)(qw + l15) * DP + g * 8;
        #pragma unroll
        for (int t = 0; t < 10; ++t) {
            qh[t] = *(const half8*)(ph + t * 32);
            ql[t] = *(const half8*)(pl + t * 32);
        }
    }
    // Force Q loads complete BEFORE the loop (keeps compiler vmcnt waits out of the loop)
    #pragma unroll
    for (int t = 0; t < 10; ++t) asm volatile("" :: "v"(qh[t]), "v"(ql[t]));

    // Vh staging source offsets (pre-swizzled source, linear LDS dst — verified R2 pattern)
    const char* gb = (const char*)gvh;
    unsigned soff[5];
    #pragma unroll
    for (int i = 0; i < 5; ++i) {
        const int j = i * 4 + wv;            // unit 0..19
        const int u = j * 64 + lane;         // 0..1279
        const int row = u / 40, s = u - row * 40;
        soff[i] = (unsigned)(vs0 * 640 + row * 640 + ((s ^ (row & 7)) << 4));
    }

    // Vt A-frag global pointers: af[nbi] = Vt[n = (nbi*4+wv)*16 + l15][v = vs0 + g*8 ..+7]
    const char* vtp[5];
    #pragma unroll
    for (int i = 0; i < 5; ++i) {
        const int n = (i * 4 + wv) * 16 + l15;
        vtp[i] = (const char*)gvt + ((size_t)n * VP + vs0 + g * 8) * 2;
    }

    floatx4 O[5][4];
    #pragma unroll
    for (int a = 0; a < 5; ++a)
        #pragma unroll
        for (int b = 0; b < 4; ++b) O[a][b] = (floatx4){0.f, 0.f, 0.f, 0.f};
    float mx[4] = {-1e30f, -1e30f, -1e30f, -1e30f};
    float ls[4] = {0.f, 0.f, 0.f, 0.f};

    char*  Pb  = sm + 40960;
    float* scb = (float*)(sm + 45056);

    // prologue: stage tile 0 into buf0, full drain (outside loop, cheap once)
    #pragma unroll
    for (int i = 0; i < 5; ++i) {
        gload16(gb + soff[i], sm + ((i * 4 + wv) << 10));
        soff[i] += 20480;
    }
    __builtin_amdgcn_sched_barrier(0);
    asm volatile("s_waitcnt vmcnt(0)" ::: "memory");
    __builtin_amdgcn_s_barrier();
    __builtin_amdgcn_sched_barrier(0);

    for (int tau = 0; tau < NTILE; ++tau) {
        const char* buf = sm + (tau & 1) * 20480;
        char*       nxt = sm + ((tau + 1) & 1) * 20480;

        // ---- issue af(t) reg loads FIRST (5x global_load_dwordx4) ----
        uintx4 afr[5];
        #pragma unroll
        for (int i = 0; i < 5; ++i) {
            asm volatile("global_load_dwordx4 %0, %1, off"
                         : "=v"(afr[i]) : "v"(vtp[i]) : "memory");
            vtp[i] += 64;
        }
        __builtin_amdgcn_sched_barrier(0);
        // ---- then issue Vh(t+1) staging (always, junk read past end on last tile is harmless) ----
        #pragma unroll
        for (int i = 0; i < 5; ++i) {
            gload16(gb + soff[i], nxt + ((i * 4 + wv) << 10));
            soff[i] += 20480;
        }
        __builtin_amdgcn_sched_barrier(0);
        // ---- (a): Vh(t) landed everywhere; af(t) + Vh(t+1) stay in flight ----
        asm volatile("s_waitcnt vmcnt(10)" ::: "memory");
        __builtin_amdgcn_s_barrier();
        __builtin_amdgcn_sched_barrier(0);

        // ---- QK^T: S[16 q][32 v], 2-term fp16 (verified R2 addressing) ----
        floatx4 s0 = {0.f,0.f,0.f,0.f}, s1 = {0.f,0.f,0.f,0.f};
        __builtin_amdgcn_s_setprio(1);
        #pragma unroll
        for (int t = 0; t < 10; ++t) {
            const int koff = (t * 4 + g) << 4;
            half8 bh0 = *(const half8*)(buf + l15 * 640 + (koff ^ swz0));
            half8 bh1 = *(const half8*)(buf + (l15 + 16) * 640 + (koff ^ swz0));
            s0 = __builtin_amdgcn_mfma_f32_16x16x32_f16(qh[t], bh0, s0, 0, 0, 0);
            s0 = __builtin_amdgcn_mfma_f32_16x16x32_f16(ql[t], bh0, s0, 0, 0, 0);
            s1 = __builtin_amdgcn_mfma_f32_16x16x32_f16(qh[t], bh1, s1, 0, 0, 0);
            s1 = __builtin_amdgcn_mfma_f32_16x16x32_f16(ql[t], bh1, s1, 0, 0, 0);
        }
        __builtin_amdgcn_s_setprio(0);
        const int vbase = vs0 + tau * BK;
        if (vbase + l15 >= VOCAB)      { s0[0]=-1e30f; s0[1]=-1e30f; s0[2]=-1e30f; s0[3]=-1e30f; }
        if (vbase + 16 + l15 >= VOCAB) { s1[0]=-1e30f; s1[1]=-1e30f; s1[2]=-1e30f; s1[3]=-1e30f; }

        // ---- online softmax, defer-max THR=8 (verified R2) ----
        unsigned short pu0[4], pu1[4]; float scv[4];
        #pragma unroll
        for (int r = 0; r < 4; ++r) {
            float tm = red16_max(fmaxf(s0[r], s1[r]));
            bool grow = tm > mx[r] + 8.0f;
            float nm = grow ? tm : mx[r];
            float sc = grow ? __expf(mx[r] - nm) : 1.0f;
            mx[r] = nm;
            float p0 = __expf(s0[r] - nm);
            float p1 = __expf(s1[r] - nm);
            pu0[r] = f2h(p0); pu1[r] = f2h(p1);
            float ps = red16_sum(h2f(pu0[r]) + h2f(pu1[r]));
            ls[r] = ls[r] * sc + ps;
            scv[r] = sc;
        }
        // ---- publish P (rows unit-swizzled by (q>>1)&3) + sc ----
        #pragma unroll
        for (int r = 0; r < 4; ++r) {
            const int q = wv * 16 + g * 4 + r;
            const int x = (q >> 1) & 3;
            char* prow = Pb + q * 64 + (l15 & 7) * 2;
            *(unsigned short*)(prow + (((l15 >> 3) ^ x) << 4))       = pu0[r];
            *(unsigned short*)(prow + ((((l15 >> 3) + 2) ^ x) << 4)) = pu1[r];
        }
        if (l15 == 0) {
            #pragma unroll
            for (int r = 0; r < 4; ++r) scb[wv * 16 + g * 4 + r] = scv[r];
        }
        // ---- (b): P visible; prefetch still in flight ----
        __builtin_amdgcn_sched_barrier(0);
        asm volatile("s_waitcnt lgkmcnt(0)" ::: "memory");
        __builtin_amdgcn_s_barrier();
        __builtin_amdgcn_sched_barrier(0);
        // ---- drain af(t) only (Vh(t+1) keeps flying) ----
        asm volatile("s_waitcnt vmcnt(5)" ::: "memory");
        __builtin_amdgcn_sched_barrier(0);

        // ---- PV in O^T form ----
        half8 pf[4];
        #pragma unroll
        for (int qb = 0; qb < 4; ++qb) {
            const int q = qb * 16 + l15;
            pf[qb] = *(const half8*)(Pb + q * 64 + ((g ^ ((q >> 1) & 3)) << 4));
        }
        #pragma unroll
        for (int qb = 0; qb < 4; ++qb) {
            float sc = scb[qb * 16 + l15];
            if (__any(sc != 1.0f)) {
                #pragma unroll
                for (int nbi = 0; nbi < 5; ++nbi) O[nbi][qb] *= sc;
            }
        }
        __builtin_amdgcn_s_setprio(1);
        #pragma unroll
        for (int nbi = 0; nbi < 5; ++nbi) {
            half8 af = __builtin_bit_cast(half8, afr[nbi]);
            #pragma unroll
            for (int qb = 0; qb < 4; ++qb)
                O[nbi][qb] = __builtin_amdgcn_mfma_f32_16x16x32_f16(af, pf[qb], O[nbi][qb], 0, 0, 0);
        }
        __builtin_amdgcn_s_setprio(0);
        // no end-of-tile barrier needed: (a) of the next tile orders P/buf reuse
    }

    // drain leftover junk prefetch before LDS dealloc / stores
    asm volatile("s_waitcnt vmcnt(0)" ::: "memory");

    // ---- store partials ----
    #pragma unroll
    for (int nbi = 0; nbi < 5; ++nbi) {
        const int nb = nbi * 4 + wv;
        #pragma unroll
        for (int qb = 0; qb < 4; ++qb) {
            float* op = opart + ((size_t)bs * N_ROWS + qblk + qb * 16 + l15) * DP + nb * 16 + g * 4;
            *(floatx4*)op = O[nbi][qb];
        }
    }
    if (l15 == 0) {
        #pragma unroll
        for (int r = 0; r < 4; ++r) {
            mpart[(size_t)bs * N_ROWS + qw + g * 4 + r] = mx[r];
            lpart[(size_t)bs * N_ROWS + qw + g * 4 + r] = ls[r];
        }
    }
}

// ---------------- kernel 4: combine slice partials + default column (verified R2) ----------------
__global__ __launch_bounds__(256) void k_combine(const float* __restrict__ words,
                                                 const float* __restrict__ sdef,
                                                 const float* __restrict__ opart,
                                                 const float* __restrict__ mpart,
                                                 const float* __restrict__ lpart,
                                                 float* __restrict__ out) {
    const int gid = blockIdx.x * 256 + threadIdx.x;
    const int q = gid / DP;
    const int d = gid % DP;
    if (q >= N_ROWS) return;
    float sd = sdef[q];
    float M = sd;
    #pragma unroll
    for (int j = 0; j < VSLICE; ++j) M = fmaxf(M, mpart[(size_t)j * N_ROWS + q]);
    float ed = __expf(sd - M);
    float denom = ed;
    float acc = (d < DIM) ? ed * words[(size_t)q * DIM + d] : 0.f;
    #pragma unroll
    for (int j = 0; j < VSLICE; ++j) {
        float e = __expf(mpart[(size_t)j * N_ROWS + q] - M);
        denom += lpart[(size_t)j * N_ROWS + q] * e;
        acc += e * opart[((size_t)j * N_ROWS + q) * DP + d];
    }
    if (d < DIM) out[(size_t)q * DIM + d] = acc / denom;
}

// ---------------- launcher ----------------
extern "C" void kernel_launch(void* const* d_in, const int* in_sizes, int n_in,
                              void* d_out, int out_size, void* d_ws, size_t ws_size,
                              hipStream_t stream) {
    const float* words = (const float*)d_in[0];
    const float* vocab = (const float*)d_in[1];
    const float* de    = (const float*)d_in[2];
    const float* W     = (const float*)d_in[3];

    char* ws = (char*)d_ws;
    unsigned short* proj_hi = (unsigned short*)(ws + OFF_PROJ_HI);
    unsigned short* proj_lo = (unsigned short*)(ws + OFF_PROJ_LO);
    float*          sdef    = (float*)(ws + OFF_SDEF);
    unsigned short* vh      = (unsigned short*)(ws + OFF_VH);
    unsigned short* vt      = (unsigned short*)(ws + OFF_VT);
    float*          opart   = (float*)(ws + OFF_OP);
    float*          mpart   = (float*)(ws + OFF_MP);
    float*          lpart   = (float*)(ws + OFF_LP);

    hipLaunchKernelGGL(k_proj,    dim3(N_ROWS / 16), dim3(256), 0, stream,
                       words, W, de, proj_hi, proj_lo, sdef);
    hipLaunchKernelGGL(k_vocab,   dim3(784 * 5), dim3(256), 0, stream,
                       vocab, vh, vt);
    hipLaunchKernelGGL(k_attn,    dim3(RB * VSLICE), dim3(256), 0, stream,
                       proj_hi, proj_lo, vh, vt, opart, mpart, lpart);
    hipLaunchKernelGGL(k_combine, dim3((N_ROWS * DP) / 256), dim3(256), 0, stream,
                       words, sdef, opart, mpart, lpart, (float*)d_out);
}